// Round 17
// baseline (942.948 us; speedup 1.0000x reference)
//
#include <hip/hip_runtime.h>
#include <hip/hip_bf16.h>

#define TOK 8192      // B*S tokens
#define DD 1024       // D
#define FF 4096       // F
#define EE 8          // experts
#define NPAIR 16384   // TOK*K

typedef __attribute__((ext_vector_type(8))) short short8;
typedef __attribute__((ext_vector_type(4))) short short4v;
typedef __attribute__((ext_vector_type(4))) float f32x4;

#define VMCNT8()  asm volatile("s_waitcnt vmcnt(8)" ::: "memory")
#define VMCNT0()  asm volatile("s_waitcnt vmcnt(0)" ::: "memory")
#define BARRIER() asm volatile("s_barrier" ::: "memory")

// async global->LDS, 16B per lane. LDS dest = wave-uniform base + lane*16 (linear).
__device__ __forceinline__ void async16(const void* g, void* l) {
  __builtin_amdgcn_global_load_lds((const __attribute__((address_space(1))) void*)g,
                                   (__attribute__((address_space(3))) void*)l, 16, 0, 0);
}

__device__ __forceinline__ short bfc(float f) {
  return __builtin_bit_cast(short, (__bf16)f);   // RNE f32->bf16
}
__device__ __forceinline__ float b2f(short s) {
  return __builtin_bit_cast(float, ((unsigned)(unsigned short)s) << 16);
}
__device__ __forceinline__ short8 cvt8(f32x4 a, f32x4 b) {
  short8 r;
  r[0]=bfc(a[0]); r[1]=bfc(a[1]); r[2]=bfc(a[2]); r[3]=bfc(a[3]);
  r[4]=bfc(b[0]); r[5]=bfc(b[1]); r[6]=bfc(b[2]); r[7]=bfc(b[3]);
  return r;
}

#define MFMA_BF16 __builtin_amdgcn_mfma_f32_16x16x32_bf16

// ---------------- f32 -> bf16 pack (grid-stride; NT loads: f32 src read-once) ----------------
__global__ __launch_bounds__(256) void cvt_bf16_kernel(const float* __restrict__ src,
                                                       short* __restrict__ dst, int n8) {
  int i = blockIdx.x * 256 + threadIdx.x;
  const int stride = gridDim.x * 256;
  for (; i < n8; i += stride) {
    f32x4 a = __builtin_nontemporal_load(&((const f32x4*)src)[2*i]);
    f32x4 b = __builtin_nontemporal_load(&((const f32x4*)src)[2*i + 1]);
    ((short8*)dst)[i] = cvt8(a, b);
  }
}

// ---------------- interleave wg/w1 -> wB[e][2F][D] bf16 ----------------
// f -> group g=f>>4, j=f&15. wg row f -> wB row 32g+j; w1 row f -> wB row 32g+16+j.
__global__ __launch_bounds__(256) void cvt_interleave(const float* __restrict__ wgw,
    const float* __restrict__ w1w, short* __restrict__ wB) {
  const int b = blockIdx.x;          // e*FF + f
  const int e = b >> 12;             // FF = 4096
  const int f = b & 4095;
  const int g = f >> 4, j = f & 15;
  const int tid = threadIdx.x;
  const int u = tid & 127;           // 128 units of 8 f32 per row
  const float* src = ((tid < 128) ? wgw : w1w) + (size_t)b * DD;
  const size_t drow = (size_t)e * (2*FF) + 32*g + j + ((tid < 128) ? 0 : 16);
  f32x4 a = __builtin_nontemporal_load(&((const f32x4*)src)[2*u]);
  f32x4 c = __builtin_nontemporal_load(&((const f32x4*)src)[2*u + 1]);
  ((short8*)(wB + drow * DD))[u] = cvt8(a, c);
}

// ---------------- router: softmax -> top2 -> lists/gates/eids; emits xb (bf16 x) -------------
__global__ __launch_bounds__(64) void router_kernel(const float* __restrict__ x,
    const float* __restrict__ rw, int* __restrict__ counts, int* __restrict__ lists,
    float* __restrict__ gates, int* __restrict__ eids, short* __restrict__ xb, int write_xb) {
  const int t = blockIdx.x;
  const int l = threadIdx.x;
  const f32x4* xr = (const f32x4*)(x + (size_t)t * DD);
  f32x4 xv[4];
#pragma unroll
  for (int i = 0; i < 4; i++) xv[i] = xr[l + 64 * i];
  if (write_xb) {
    short4v* xo = (short4v*)(xb + (size_t)t * DD);
#pragma unroll
    for (int i = 0; i < 4; i++) {
      short4v o; o[0]=bfc(xv[i][0]); o[1]=bfc(xv[i][1]); o[2]=bfc(xv[i][2]); o[3]=bfc(xv[i][3]);
      xo[l + 64 * i] = o;
    }
  }
  float lg[EE];
#pragma unroll
  for (int e = 0; e < EE; e++) {
    const f32x4* wr = (const f32x4*)(rw + e * DD);
    float s = 0.f;
#pragma unroll
    for (int i = 0; i < 4; i++) {
      f32x4 w = wr[l + 64 * i];
      s += xv[i][0]*w[0] + xv[i][1]*w[1] + xv[i][2]*w[2] + xv[i][3]*w[3];
    }
#pragma unroll
    for (int off = 32; off > 0; off >>= 1) s += __shfl_down(s, off, 64);
    lg[e] = s;
  }
  if (l == 0) {
    float mx = lg[0];
#pragma unroll
    for (int e = 1; e < EE; e++) mx = fmaxf(mx, lg[e]);
    float p[EE]; float den = 0.f;
#pragma unroll
    for (int e = 0; e < EE; e++) { p[e] = expf(lg[e] - mx); den += p[e]; }
    int i1 = 0;
#pragma unroll
    for (int e = 1; e < EE; e++) if (p[e] > p[i1]) i1 = e;
    int i2 = (i1 == 0) ? 1 : 0;
#pragma unroll
    for (int e = 0; e < EE; e++) if (e != i1 && p[e] > p[i2]) i2 = e;
    float inv = 1.f / den;
    gates[t*2+0] = p[i1] * inv;  eids[t*2+0] = i1;
    gates[t*2+1] = p[i2] * inv;  eids[t*2+1] = i2;
    int p1 = atomicAdd(&counts[i1], 1); lists[i1*TOK + p1] = t*2 + 0;
    int p2 = atomicAdd(&counts[i2], 1); lists[i2*TOK + p2] = t*2 + 1;
  }
}

// ============================================================================
// stage A: 256x128 tile, BK=64, single-buffered 48 KB LDS, m97 2-barrier loop.
// acc[4][4]=64 AGPR + ~60 VGPR = 124 regs -> 16-wave cap; (512,4) pins it.
// 2 blocks/CU x 8 waves. 128-byte LDS rows, swz8 slot^=(row&7): zero conflicts.
// BX-FASTEST ordering: concurrent blocks share one 0.25 MB weight panel (L2);
// x is tiny (32 MB total, L3-resident) so its re-streams never reach HBM.
// Weights then stream ~once per expert -> FETCH ~134+16 MB (was 580 MB
// with by-fastest, which re-streamed the 33.5 MB/expert slab per bx-round).
// ============================================================================
#define STG3(t) do { const int ko=(t)*64;                                      \
    _Pragma("unroll")                                                          \
    for (int p = 0; p < 4; p++)                                                \
      async16(aS[p] + ko, &ldsm[p*4096 + wid*512]);                            \
    _Pragma("unroll")                                                          \
    for (int p = 0; p < 2; p++)                                                \
      async16(bS[p] + ko, &ldsm[16384 + p*4096 + wid*512]);                    \
    } while(0)

#define RD_A(kk, mi) (*(const short8*)&ldsm[(wr*64+(mi)*16+ln15)*64 + ((((kk)*4+g) ^ ((wr*64+(mi)*16+ln15)&7))*8)])
#define RD_B(kk, ni) (*(const short8*)&ldsm[16384 + (wc*64+(ni)*16+ln15)*64 + ((((kk)*4+g) ^ ((wc*64+(ni)*16+ln15)&7))*8)])

__global__ __launch_bounds__(512, 4) void stage_a97(
    const short* __restrict__ xb, const short* __restrict__ wB,
    const float* __restrict__ wgb, const float* __restrict__ w1b,
    const int* __restrict__ counts, const int* __restrict__ lists,
    short* __restrict__ hbuf, int f0chunk, int Fc) {

  // bijective XCD swizzle; BX fastest within expert (weight-panel sharing).
  const int NBX = gridDim.x, NBY = gridDim.y;
  const int q = NBX * NBY;
  const int lin = blockIdx.x + NBX * (blockIdx.y + NBY * blockIdx.z);
  const int orig = (lin & 7) * q + (lin >> 3);
  const int e = orig / q;
  const int m = orig - e * q;
  const int bx = m % NBX;
  const int by = m / NBX;

  const int cnt = counts[e];
  const int row0 = bx * 256;
  if (row0 >= cnt) return;
  const int R0 = f0chunk * 2 + by * 128;   // wB row base within expert

  __shared__ short ldsm[24576];   // 48 KB: A 256x64 + B 128x64
  __shared__ int s_pair[256];

  const int tid = threadIdx.x;
  const int wid = tid >> 6;
  const int lane = tid & 63;
  const int ln15 = lane & 15, g = lane >> 4;
  const int wr = wid >> 1, wc = wid & 1;   // 4M x 2N waves, 64x64 each

  if (tid < 256) {
    int r = row0 + tid;
    s_pair[tid] = (r < cnt) ? lists[e*TOK + r] : 0;
  }
  __syncthreads();

  const short* aS[4]; const short* bS[2];
#pragma unroll
  for (int p = 0; p < 4; p++) {
    int j = p * 512 + tid;
    int r = j >> 3;
    int sl = (j & 7) ^ (r & 7);
    aS[p] = xb + (size_t)(s_pair[r] >> 1) * DD + sl * 8;
  }
#pragma unroll
  for (int p = 0; p < 2; p++) {
    int j = p * 512 + tid;
    int r = j >> 3;            // [0,128)
    int sl = (j & 7) ^ (r & 7);
    bS[p] = wB + ((size_t)e * (2*FF) + R0 + r) * DD + sl * 8;
  }

  f32x4 acc[4][4] = {};

  for (int t = 0; t < 16; t++) {
    STG3(t);
    __syncthreads();   // compiler drains vmcnt(0) (m97 semantics)
#pragma unroll
    for (int kk = 0; kk < 2; kk++) {
      short8 a[4], b[4];
#pragma unroll
      for (int mi = 0; mi < 4; mi++) a[mi] = RD_A(kk, mi);
#pragma unroll
      for (int ni = 0; ni < 4; ni++) b[ni] = RD_B(kk, ni);
#pragma unroll
      for (int mi = 0; mi < 4; mi++)
#pragma unroll
        for (int ni = 0; ni < 4; ni++)
          acc[mi][ni] = MFMA_BF16(a[mi], b[ni], acc[mi][ni], 0, 0, 0);
    }
    __syncthreads();
  }

  // epilogue: ni even = hg cols, ni odd = h1 cols, same f.
  const float* wgb_e = wgb + e * FF;
  const float* w1b_e = w1b + e * FF;
  float bgv[2], b1v[2]; int fl[2];
#pragma unroll
  for (int m2 = 0; m2 < 2; m2++) {
    int fg = (R0 + wc*64 + m2*32) / 2 + ln15;
    bgv[m2] = wgb_e[fg];
    b1v[m2] = w1b_e[fg];
    fl[m2] = fg - f0chunk;
  }
#pragma unroll
  for (int mi = 0; mi < 4; mi++) {
    int trb = wr*64 + mi*16 + (g << 2);
#pragma unroll
    for (int m2 = 0; m2 < 2; m2++) {
#pragma unroll
      for (int j = 0; j < 4; j++) {
        int tr = trb + j;
        if (row0 + tr < cnt) {
          int pair = s_pair[tr];
          float hg = acc[mi][2*m2][j] + bgv[m2];
          float h1 = acc[mi][2*m2+1][j] + b1v[m2];
          float gl = 0.5f * hg * (1.f + erff(hg * 0.70710678118f));
          hbuf[(size_t)pair * Fc + fl[m2]] = bfc(gl * h1);
        }
      }
    }
  }
}

// ============================================================================
// stage B: 128x128 tile, BK=64, 33 KB LDS, (256,4) -> 4 blocks/CU x 4 waves.
// BX-FASTEST: concurrent blocks share one w2 panel (L2); hbuf re-streams
// come from L3 (134 MB). ybuf BF16 NT (write-once / read-once).
// ============================================================================
__global__ __launch_bounds__(256, 4) void stage_b97(
    const short* __restrict__ hbuf, const short* __restrict__ w2wb,
    const int* __restrict__ counts, const int* __restrict__ lists,
    short* __restrict__ ybuf, int Fc) {

  const int NBX = gridDim.x, NBY = gridDim.y;
  const int q = NBX * NBY;
  const int lin = blockIdx.x + NBX * (blockIdx.y + NBY * blockIdx.z);
  const int orig = (lin & 7) * q + (lin >> 3);
  const int e = orig / q;
  const int m = orig - e * q;
  const int bx = m % NBX;
  const int by = m / NBX;

  const int cnt = counts[e];
  const int row0 = bx * 128;
  if (row0 >= cnt) return;
  const int d0 = by * 128;

  __shared__ short lA[128 * 64];   // 16 KB
  __shared__ short lB[128 * 64];   // 16 KB
  __shared__ int s_pair[128];

  const int tid = threadIdx.x;
  const int wid = tid >> 6;
  const int lane = tid & 63;
  const int ln15 = lane & 15, g = lane >> 4;
  const int wr = wid >> 1, wc = wid & 1;   // 2M x 2N waves, 64x64 each

  if (tid < 128) {
    int r = row0 + tid;
    s_pair[tid] = (r < cnt) ? lists[e*TOK + r] : 0;
  }
  __syncthreads();

  const short* aS[4]; const short* bS[4];
#pragma unroll
  for (int p = 0; p < 4; p++) {
    int j = p * 256 + tid;
    int r = j >> 3;
    int sl = (j & 7) ^ (r & 7);
    aS[p] = hbuf + (size_t)s_pair[r] * Fc + sl * 8;
    bS[p] = w2wb + ((size_t)e * DD + d0 + r) * FF + sl * 8;
  }

  f32x4 acc[4][4] = {};
  const int NT = Fc >> 6;

  for (int t = 0; t < NT; t++) {
    const int ko = t * 64;
#pragma unroll
    for (int p = 0; p < 4; p++) {
      async16(aS[p] + ko, &lA[p*2048 + wid*512]);
      async16(bS[p] + ko, &lB[p*2048 + wid*512]);
    }
    __syncthreads();
#pragma unroll
    for (int kk = 0; kk < 2; kk++) {
      short8 a[4], b[4];
#pragma unroll
      for (int mi = 0; mi < 4; mi++) {
        int r = wr*64 + mi*16 + ln15;
        a[mi] = *(const short8*)&lA[r*64 + (((kk*4 + g) ^ (r & 7)) * 8)];
      }
#pragma unroll
      for (int ni = 0; ni < 4; ni++) {
        int r = wc*64 + ni*16 + ln15;
        b[ni] = *(const short8*)&lB[r*64 + (((kk*4 + g) ^ (r & 7)) * 8)];
      }
#pragma unroll
      for (int mi = 0; mi < 4; mi++)
#pragma unroll
        for (int ni = 0; ni < 4; ni++)
          acc[mi][ni] = MFMA_BF16(a[mi], b[ni], acc[mi][ni], 0, 0, 0);
    }
    __syncthreads();
  }

  // epilogue: bf16 NT stores (ybuf written-once, streamed once by combine)
#pragma unroll
  for (int mi = 0; mi < 4; mi++) {
    int trb = wr*64 + mi*16 + (g << 2);
#pragma unroll
    for (int j = 0; j < 4; j++) {
      int tr = trb + j;
      if (row0 + tr < cnt) {
        int pair = s_pair[tr];
        short* yrow = ybuf + (size_t)pair * DD;
#pragma unroll
        for (int ni = 0; ni < 4; ni++) {
          int d = d0 + wc*64 + ni*16 + ln15;
          __builtin_nontemporal_store(bfc(acc[mi][ni][j]), &yrow[d]);
        }
      }
    }
  }
}

// ---- combine: out[t] = g0*(y[2t]+b2[e0]) + g1*(y[2t+1]+b2[e1]); y is bf16 ----
__global__ __launch_bounds__(256) void combine_kernel(const short* __restrict__ yb,
    const float* __restrict__ w2b, const float* __restrict__ gates,
    const int* __restrict__ eids, float* __restrict__ out) {
  const int t = blockIdx.x;
  const int tid = threadIdx.x;
  const float g0 = gates[2*t], g1 = gates[2*t+1];
  const int e0 = eids[2*t], e1 = eids[2*t+1];
  short4v y0 = __builtin_nontemporal_load(&((const short4v*)(yb + (size_t)(2*t) * DD))[tid]);
  short4v y1 = __builtin_nontemporal_load(&((const short4v*)(yb + (size_t)(2*t+1) * DD))[tid]);
  f32x4 c0 = ((const f32x4*)(w2b + (size_t)e0 * DD))[tid];
  f32x4 c1 = ((const f32x4*)(w2b + (size_t)e1 * DD))[tid];
  f32x4 o;
#pragma unroll
  for (int i = 0; i < 4; i++) o[i] = g0 * (b2f(y0[i]) + c0[i]) + g1 * (b2f(y1[i]) + c1[i]);
  __builtin_nontemporal_store(o, &((f32x4*)(out + (size_t)t * DD))[tid]);
}

// ================= chunked-Fc fallback: atomic stage B (round-5, proven) =================
#define BB_LDS (128*64)
__global__ __launch_bounds__(256, 2) void stage_b_bf(
    const short* __restrict__ hbuf, const short* __restrict__ w2wb, const float* __restrict__ w2b,
    const int* __restrict__ counts, const int* __restrict__ lists, const float* __restrict__ gates,
    float* __restrict__ out, int f0chunk, int Fc, int addbias) {

  const int lin = blockIdx.x + 64 * (blockIdx.y + 8 * blockIdx.z);
  const int orig = (lin & 7) * 512 + (lin >> 3);
  const int bx = orig & 63;
  const int by = (orig >> 6) & 7;
  const int e  = orig >> 9;

  const int cnt = counts[e];
  const int row0 = bx * 128;
  if (row0 >= cnt) return;
  const int d0 = by * 128;

  __shared__ short lA[2 * BB_LDS];
  __shared__ short lB[2 * BB_LDS];
  __shared__ int s_pair[128];

  const int tid = threadIdx.x;
  const int wid = tid >> 6;
  const int lane = tid & 63;

  if (tid < 128) {
    int r = row0 + tid;
    s_pair[tid] = (r < cnt) ? lists[e*TOK + r] : 0;
  }
  __syncthreads();

  const short* aSrc[4]; const short* bSrc[4];
#pragma unroll
  for (int p = 0; p < 4; p++) {
    int j = p * 256 + tid;
    int r = j >> 3;
    int sl = (j & 7) ^ (r & 7);
    aSrc[p] = hbuf + (size_t)s_pair[r] * Fc + sl * 8;
    bSrc[p] = w2wb + ((size_t)e * DD + d0 + r) * FF + f0chunk + sl * 8;
  }

  f32x4 acc[4][4] = {};
  const int wr = wid >> 1, wc = wid & 1;
  const int NT = Fc >> 6;

#pragma unroll
  for (int p = 0; p < 4; p++) async16(aSrc[p], &lA[p*2048 + wid*512]);
#pragma unroll
  for (int p = 0; p < 4; p++) async16(bSrc[p], &lB[p*2048 + wid*512]);

  for (int t = 0; t < NT; t++) {
    const int cur = t & 1;
    if (t + 1 < NT) {
      const int nb = cur ^ 1;
      const int kf = (t + 1) * 64;
#pragma unroll
      for (int p = 0; p < 4; p++) async16(aSrc[p] + kf, &lA[nb*BB_LDS + p*2048 + wid*512]);
#pragma unroll
      for (int p = 0; p < 4; p++) async16(bSrc[p] + kf, &lB[nb*BB_LDS + p*2048 + wid*512]);
      VMCNT8();
    } else {
      VMCNT0();
    }
    BARRIER();

    const short* LA = lA + cur * BB_LDS;
    const short* LB = lB + cur * BB_LDS;
#pragma unroll
    for (int kk = 0; kk < 2; kk++) {
      short8 a[4], b[4];
#pragma unroll
      for (int mi = 0; mi < 4; mi++) {
        int r = wr*64 + mi*16 + (lane & 15);
        int u = (kk*4 + (lane >> 4)) ^ (r & 7);
        a[mi] = *(const short8*)(LA + r*64 + u*8);
      }
#pragma unroll
      for (int ni = 0; ni < 4; ni++) {
        int r = wc*64 + ni*16 + (lane & 15);
        int u = (kk*4 + (lane >> 4)) ^ (r & 7);
        b[ni] = *(const short8*)(LB + r*64 + u*8);
      }
#pragma unroll
      for (int mi = 0; mi < 4; mi++)
#pragma unroll
        for (int ni = 0; ni < 4; ni++)
          acc[mi][ni] = MFMA_BF16(a[mi], b[ni], acc[mi][ni], 0, 0, 0);
    }
    BARRIER();
  }

  const float* w2b_e = w2b + e * DD;
#pragma unroll
  for (int mi = 0; mi < 4; mi++) {
    int trb = wr*64 + mi*16 + ((lane >> 4) << 2);
#pragma unroll
    for (int j = 0; j < 4; j++) {
      int tr = trb + j;
      if (row0 + tr < cnt) {
        int pair = s_pair[tr];
        int t = pair >> 1;
        float gt = gates[pair];
        float* orow = out + (size_t)t * DD;
#pragma unroll
        for (int ni = 0; ni < 4; ni++) {
          int d = d0 + wc*64 + ni*16 + (lane & 15);
          float v = acc[mi][ni][j] * gt;
          if (addbias) v += w2b_e[d] * gt;
          atomicAdd(orow + d, v);
        }
      }
    }
  }
}

// ================= legacy f32 fallback (tiny ws) =================
__global__ __launch_bounds__(256, 2) void stage_a_f32(
    const float* __restrict__ x, const float* __restrict__ wgw, const float* __restrict__ wgb,
    const float* __restrict__ w1w, const float* __restrict__ w1b,
    const int* __restrict__ counts, const int* __restrict__ lists,
    short* __restrict__ hbuf, int f0chunk, int Fc) {

  const int e = blockIdx.z;
  const int cnt = counts[e];
  const int row0 = blockIdx.x * 128;
  if (row0 >= cnt) return;
  const int fc0 = blockIdx.y * 128;
  const int fg0 = f0chunk + fc0;

  __shared__ float lA[128 * 32];
  __shared__ float lBg[128 * 32];
  __shared__ float lB1[128 * 32];
  __shared__ int s_pair[128];

  const int tid = threadIdx.x;
  const int wid = tid >> 6;
  const int lane = tid & 63;

  if (tid < 128) {
    int r = row0 + tid;
    s_pair[tid] = (r < cnt) ? lists[e*TOK + r] : 0;
  }
  __syncthreads();

  const float* aSrc[4]; const float* gSrc[4]; const float* oSrc[4];
#pragma unroll
  for (int p = 0; p < 4; p++) {
    int j = p * 256 + tid;
    int r = j >> 3;
    int sl = (j & 7) ^ (r & 7);
    aSrc[p] = x + (size_t)(s_pair[r] >> 1) * DD + sl * 4;
    gSrc[p] = wgw + ((size_t)e * FF + fg0 + r) * DD + sl * 4;
    oSrc[p] = w1w + ((size_t)e * FF + fg0 + r) * DD + sl * 4;
  }

  f32x4 accg[4][4] = {}; f32x4 acc1[4][4] = {};
  const int wr = wid >> 1, wc = wid & 1;

  for (int k0 = 0; k0 < DD; k0 += 32) {
#pragma unroll
    for (int p = 0; p < 4; p++) async16(aSrc[p] + k0, &lA[p*1024 + wid*256]);
#pragma unroll
    for (int p = 0; p < 4; p++) async16(gSrc[p] + k0, &lBg[p*1024 + wid*256]);
#pragma unroll
    for (int p = 0; p < 4; p++) async16(oSrc[p] + k0, &lB1[p*1024 + wid*256]);
    __syncthreads();

    short8 a[4], bg[4], b1[4];
#pragma unroll
    for (int mi = 0; mi < 4; mi++) {
      int r = wr*64 + mi*16 + (lane & 15);
      int g2 = (lane >> 4) * 2;
      const f32x4* Ar = (const f32x4*)&lA[r * 32];
      a[mi] = cvt8(Ar[g2 ^ (r & 7)], Ar[(g2 + 1) ^ (r & 7)]);
    }
#pragma unroll
    for (int ni = 0; ni < 4; ni++) {
      int r = wc*64 + ni*16 + (lane & 15);
      int g2 = (lane >> 4) * 2;
      const f32x4* Bg = (const f32x4*)&lBg[r * 32];
      const f32x4* B1 = (const f32x4*)&lB1[r * 32];
      bg[ni] = cvt8(Bg[g2 ^ (r & 7)], Bg[(g2 + 1) ^ (r & 7)]);
      b1[ni] = cvt8(B1[g2 ^ (r & 7)], B1[(g2 + 1) ^ (r & 7)]);
    }
#pragma unroll
    for (int mi = 0; mi < 4; mi++)
#pragma unroll
      for (int ni = 0; ni < 4; ni++) {
        accg[mi][ni] = MFMA_BF16(a[mi], bg[ni], accg[mi][ni], 0, 0, 0);
        acc1[mi][ni] = MFMA_BF16(a[mi], b1[ni], acc1[mi][ni], 0, 0, 0);
      }
    __syncthreads();
  }

  const float* wgb_e = wgb + e * FF;
  const float* w1b_e = w1b + e * FF;
#pragma unroll
  for (int mi = 0; mi < 4; mi++) {
    int trb = wr*64 + mi*16 + ((lane >> 4) << 2);
#pragma unroll
    for (int ni = 0; ni < 4; ni++) {
      int c = wc*64 + ni*16 + (lane & 15);
      float bgv = wgb_e[fg0 + c];
      float b1v = w1b_e[fg0 + c];
#pragma unroll
      for (int j = 0; j < 4; j++) {
        int tr = trb + j;
        if (row0 + tr < cnt) {
          int pair = s_pair[tr];
          float hg = accg[mi][ni][j] + bgv;
          float h1 = acc1[mi][ni][j] + b1v;
          float gl = 0.5f * hg * (1.f + erff(hg * 0.70710678118f));
          hbuf[(size_t)pair * Fc + fc0 + c] = bfc(gl * h1);
        }
      }
    }
  }
}

__global__ __launch_bounds__(256, 2) void stage_b_f32(
    const short* __restrict__ hbuf, const float* __restrict__ w2w, const float* __restrict__ w2b,
    const int* __restrict__ counts, const int* __restrict__ lists, const float* __restrict__ gates,
    float* __restrict__ out, int f0chunk, int Fc, int addbias) {

  const int e = blockIdx.z;
  const int cnt = counts[e];
  const int row0 = blockIdx.x * 128;
  if (row0 >= cnt) return;
  const int d0 = blockIdx.y * 128;

  __shared__ short lA[128 * 64];
  __shared__ float lB[128 * 64];
  __shared__ int s_pair[128];

  const int tid = threadIdx.x;
  const int wid = tid >> 6;
  const int lane = tid & 63;

  if (tid < 128) {
    int r = row0 + tid;
    s_pair[tid] = (r < cnt) ? lists[e*TOK + r] : 0;
  }
  __syncthreads();

  const short* aSrc[4];
#pragma unroll
  for (int p = 0; p < 4; p++) {
    int j = p * 256 + tid;
    int r = j >> 3;
    int sl = (j & 7) ^ (r & 7);
    aSrc[p] = hbuf + (size_t)s_pair[r] * Fc + sl * 8;
  }
  const float* bSrc[8];
#pragma unroll
  for (int p = 0; p < 8; p++) {
    int j = p * 256 + tid;
    int r = j >> 4;
    int sl = (j & 15) ^ (r & 7);
    bSrc[p] = w2w + ((size_t)e * DD + d0 + r) * FF + f0chunk + sl * 4;
  }

  f32x4 acc[4][4] = {};
  const int wr = wid >> 1, wc = wid & 1;

  for (int kf = 0; kf < Fc; kf += 64) {
#pragma unroll
    for (int p = 0; p < 4; p++) async16(aSrc[p] + kf, &lA[p*2048 + wid*512]);
#pragma unroll
    for (int p = 0; p < 8; p++) async16(bSrc[p] + kf, &lB[p*1024 + wid*256]);
    __syncthreads();

#pragma unroll
    for (int kk = 0; kk < 2; kk++) {
      short8 a[4]; short8 b[4];
#pragma unroll
      for (int mi = 0; mi < 4; mi++) {
        int r = wr*64 + mi*16 + (lane & 15);
        int u = (kk*4 + (lane >> 4)) ^ (r & 7);
        a[mi] = ((const short8*)(lA + r * 64))[u];
      }
#pragma unroll
      for (int ni = 0; ni < 4; ni++) {
        int r = wc*64 + ni*16 + (lane & 15);
        int g2 = (kk*4 + (lane >> 4)) * 2;
        const f32x4* Br = (const f32x4*)(lB + r * 64);
        b[ni] = cvt8(Br[g2 ^ (r & 7)], Br[(g2 + 1) ^ (r & 7)]);
      }
#pragma unroll
      for (int mi = 0; mi < 4; mi++)
#pragma unroll
        for (int ni = 0; ni < 4; ni++)
          acc[mi][ni] = MFMA_BF16(a[mi], b[ni], acc[mi][ni], 0, 0, 0);
    }
    __syncthreads();
  }

  const float* w2b_e = w2b + e * DD;
#pragma unroll
  for (int mi = 0; mi < 4; mi++) {
    int trb = wr*64 + mi*16 + ((lane >> 4) << 2);
#pragma unroll
    for (int j = 0; j < 4; j++) {
      int tr = trb + j;
      if (row0 + tr < cnt) {
        int pair = s_pair[tr];
        int t = pair >> 1;
        float gt = gates[pair];
        float* orow = out + (size_t)t * DD;
#pragma unroll
        for (int ni = 0; ni < 4; ni++) {
          int d = d0 + wc*64 + ni*16 + (lane & 15);
          float v = acc[mi][ni][j] * gt;
          if (addbias) v += w2b_e[d] * gt;
          atomicAdd(orow + d, v);
        }
      }
    }
  }
}

extern "C" void kernel_launch(void* const* d_in, const int* in_sizes, int n_in,
                              void* d_out, int out_size, void* d_ws, size_t ws_size,
                              hipStream_t stream) {
  const float* x   = (const float*)d_in[0];
  const float* rw  = (const float*)d_in[1];
  const float* w1w = (const float*)d_in[2];
  const float* w1b = (const float*)d_in[3];
  const float* w2w = (const float*)d_in[4];
  const float* w2b = (const float*)d_in[5];
  const float* wgw = (const float*)d_in[6];
  const float* wgb = (const float*)d_in[7];
  float* out = (float*)d_out;

  char* ws = (char*)d_ws;
  size_t off = 0;
  int* counts = (int*)(ws + off); off += 128;
  int* lists  = (int*)(ws + off); off += (size_t)EE * TOK * 4;
  float* gates = (float*)(ws + off); off += (size_t)NPAIR * 4;
  int* eids = (int*)(ws + off); off += (size_t)NPAIR * 4;
  const size_t base0 = off;

  const size_t WELEM = (size_t)EE * FF * DD;
  const size_t bf_need = base0 + (size_t)TOK*DD*2 + 2*WELEM*2 + WELEM*2;

  hipMemsetAsync(counts, 0, 128, stream);

  const int cands[6] = {4096, 2048, 1024, 512, 256, 128};

  if (bf_need + (size_t)NPAIR * 128 * 2 <= ws_size) {
    // ---- bf16 path ----
    off = base0;
    short* xb   = (short*)(ws + off); off += (size_t)TOK * DD * 2;
    short* wB   = (short*)(ws + off); off += 2 * WELEM * 2;   // interleaved wg/w1
    short* w2wb = (short*)(ws + off); off += WELEM * 2;
    short* hbuf = (short*)(ws + off);
    short* ybuf = (short*)wB;   // alias: wB dead after last stage_a (Fc==4096 only);
                                // cvt_interleave fully rewrites wB every call.

    int Fc = 128;
    for (int i = 0; i < 6; i++)
      if (off + (size_t)NPAIR * cands[i] * 2 <= ws_size) { Fc = cands[i]; break; }

    router_kernel<<<dim3(TOK), dim3(64), 0, stream>>>(x, rw, counts, lists, gates, eids, xb, 1);
    cvt_interleave<<<dim3(EE*FF), dim3(256), 0, stream>>>(wgw, w1w, wB);
    cvt_bf16_kernel<<<dim3(2048), dim3(256), 0, stream>>>(w2w, w2wb, (int)(WELEM/8));

    if (Fc == 4096) {
      // single chunk: stage_a 256x128 + stage_b 128x128 (4 blocks/CU), combine
      stage_a97<<<dim3(32, (2*Fc)/128, EE), dim3(512), 0, stream>>>(
          xb, wB, wgb, w1b, counts, lists, hbuf, 0, Fc);
      stage_b97<<<dim3(64, DD/128, EE), dim3(256), 0, stream>>>(
          hbuf, w2wb, counts, lists, ybuf, Fc);
      combine_kernel<<<dim3(TOK), dim3(256), 0, stream>>>(ybuf, w2b, gates, eids, out);
    } else {
      // chunked: stage_a + atomic stage_b
      hipMemsetAsync(out, 0, (size_t)TOK * DD * 4, stream);
      for (int f0 = 0; f0 < FF; f0 += Fc) {
        stage_a97<<<dim3(32, (2*Fc)/128, EE), dim3(512), 0, stream>>>(
            xb, wB, wgb, w1b, counts, lists, hbuf, f0, Fc);
        stage_b_bf<<<dim3(64, DD/128, EE), dim3(256), 0, stream>>>(
            hbuf, w2wb, w2b, counts, lists, gates, out, f0, Fc, f0 == 0);
      }
    }
  } else {
    // ---- legacy f32 path ----
    short* hbuf = (short*)(ws + base0);
    int Fc = 128;
    for (int i = 0; i < 6; i++)
      if (base0 + (size_t)NPAIR * cands[i] * 2 <= ws_size) { Fc = cands[i]; break; }

    hipMemsetAsync(out, 0, (size_t)TOK * DD * 4, stream);
    router_kernel<<<dim3(TOK), dim3(64), 0, stream>>>(x, rw, counts, lists, gates, eids, nullptr, 0);

    for (int f0 = 0; f0 < FF; f0 += Fc) {
      dim3 ga(64, Fc / 128, EE);
      stage_a_f32<<<ga, dim3(256), 0, stream>>>(x, wgw, wgb, w1w, w1b, counts, lists, hbuf, f0, Fc);
      dim3 gb(64, DD / 128, EE);
      stage_b_f32<<<gb, dim3(256), 0, stream>>>(hbuf, w2w, w2b, counts, lists, gates, out, f0, Fc, f0 == 0);
    }
  }
}

// Round 18
// 874.351 us; speedup vs baseline: 1.0785x; 1.0785x over previous
//
#include <hip/hip_runtime.h>
#include <hip/hip_bf16.h>

#define TOK 8192      // B*S tokens
#define DD 1024       // D
#define FF 4096       // F
#define EE 8          // experts
#define NPAIR 16384   // TOK*K

typedef __attribute__((ext_vector_type(8))) short short8;
typedef __attribute__((ext_vector_type(4))) short short4v;
typedef __attribute__((ext_vector_type(4))) float f32x4;

#define VMCNT8()  asm volatile("s_waitcnt vmcnt(8)" ::: "memory")
#define VMCNT0()  asm volatile("s_waitcnt vmcnt(0)" ::: "memory")
#define BARRIER() asm volatile("s_barrier" ::: "memory")

// async global->LDS, 16B per lane. LDS dest = wave-uniform base + lane*16 (linear).
__device__ __forceinline__ void async16(const void* g, void* l) {
  __builtin_amdgcn_global_load_lds((const __attribute__((address_space(1))) void*)g,
                                   (__attribute__((address_space(3))) void*)l, 16, 0, 0);
}

__device__ __forceinline__ short bfc(float f) {
  return __builtin_bit_cast(short, (__bf16)f);   // RNE f32->bf16
}
__device__ __forceinline__ float b2f(short s) {
  return __builtin_bit_cast(float, ((unsigned)(unsigned short)s) << 16);
}
__device__ __forceinline__ short8 cvt8(f32x4 a, f32x4 b) {
  short8 r;
  r[0]=bfc(a[0]); r[1]=bfc(a[1]); r[2]=bfc(a[2]); r[3]=bfc(a[3]);
  r[4]=bfc(b[0]); r[5]=bfc(b[1]); r[6]=bfc(b[2]); r[7]=bfc(b[3]);
  return r;
}

#define MFMA_BF16 __builtin_amdgcn_mfma_f32_16x16x32_bf16

// ---------------- f32 -> bf16 pack (grid-stride; NT loads: f32 src read-once) ----------------
__global__ __launch_bounds__(256) void cvt_bf16_kernel(const float* __restrict__ src,
                                                       short* __restrict__ dst, int n8) {
  int i = blockIdx.x * 256 + threadIdx.x;
  const int stride = gridDim.x * 256;
  for (; i < n8; i += stride) {
    f32x4 a = __builtin_nontemporal_load(&((const f32x4*)src)[2*i]);
    f32x4 b = __builtin_nontemporal_load(&((const f32x4*)src)[2*i + 1]);
    ((short8*)dst)[i] = cvt8(a, b);
  }
}

// ---------------- interleave wg/w1 -> wB[e][2F][D] bf16 ----------------
// f -> group g=f>>4, j=f&15. wg row f -> wB row 32g+j; w1 row f -> wB row 32g+16+j.
__global__ __launch_bounds__(256) void cvt_interleave(const float* __restrict__ wgw,
    const float* __restrict__ w1w, short* __restrict__ wB) {
  const int b = blockIdx.x;          // e*FF + f
  const int e = b >> 12;             // FF = 4096
  const int f = b & 4095;
  const int g = f >> 4, j = f & 15;
  const int tid = threadIdx.x;
  const int u = tid & 127;           // 128 units of 8 f32 per row
  const float* src = ((tid < 128) ? wgw : w1w) + (size_t)b * DD;
  const size_t drow = (size_t)e * (2*FF) + 32*g + j + ((tid < 128) ? 0 : 16);
  f32x4 a = __builtin_nontemporal_load(&((const f32x4*)src)[2*u]);
  f32x4 c = __builtin_nontemporal_load(&((const f32x4*)src)[2*u + 1]);
  ((short8*)(wB + drow * DD))[u] = cvt8(a, c);
}

// ---------------- router: softmax -> top2 -> lists/gates/eids; emits xb (bf16 x) -------------
__global__ __launch_bounds__(64) void router_kernel(const float* __restrict__ x,
    const float* __restrict__ rw, int* __restrict__ counts, int* __restrict__ lists,
    float* __restrict__ gates, int* __restrict__ eids, short* __restrict__ xb, int write_xb) {
  const int t = blockIdx.x;
  const int l = threadIdx.x;
  const f32x4* xr = (const f32x4*)(x + (size_t)t * DD);
  f32x4 xv[4];
#pragma unroll
  for (int i = 0; i < 4; i++) xv[i] = xr[l + 64 * i];
  if (write_xb) {
    short4v* xo = (short4v*)(xb + (size_t)t * DD);
#pragma unroll
    for (int i = 0; i < 4; i++) {
      short4v o; o[0]=bfc(xv[i][0]); o[1]=bfc(xv[i][1]); o[2]=bfc(xv[i][2]); o[3]=bfc(xv[i][3]);
      xo[l + 64 * i] = o;
    }
  }
  float lg[EE];
#pragma unroll
  for (int e = 0; e < EE; e++) {
    const f32x4* wr = (const f32x4*)(rw + e * DD);
    float s = 0.f;
#pragma unroll
    for (int i = 0; i < 4; i++) {
      f32x4 w = wr[l + 64 * i];
      s += xv[i][0]*w[0] + xv[i][1]*w[1] + xv[i][2]*w[2] + xv[i][3]*w[3];
    }
#pragma unroll
    for (int off = 32; off > 0; off >>= 1) s += __shfl_down(s, off, 64);
    lg[e] = s;
  }
  if (l == 0) {
    float mx = lg[0];
#pragma unroll
    for (int e = 1; e < EE; e++) mx = fmaxf(mx, lg[e]);
    float p[EE]; float den = 0.f;
#pragma unroll
    for (int e = 0; e < EE; e++) { p[e] = expf(lg[e] - mx); den += p[e]; }
    int i1 = 0;
#pragma unroll
    for (int e = 1; e < EE; e++) if (p[e] > p[i1]) i1 = e;
    int i2 = (i1 == 0) ? 1 : 0;
#pragma unroll
    for (int e = 0; e < EE; e++) if (e != i1 && p[e] > p[i2]) i2 = e;
    float inv = 1.f / den;
    gates[t*2+0] = p[i1] * inv;  eids[t*2+0] = i1;
    gates[t*2+1] = p[i2] * inv;  eids[t*2+1] = i2;
    int p1 = atomicAdd(&counts[i1], 1); lists[i1*TOK + p1] = t*2 + 0;
    int p2 = atomicAdd(&counts[i2], 1); lists[i2*TOK + p2] = t*2 + 1;
  }
}

// ============================================================================
// stage A: 256x128 tile, BK=64, single-buffered 48 KB LDS, m97 2-barrier loop.
// acc[4][4]=64 AGPR + ~60 VGPR = 124 regs -> 16-wave cap; (512,4) pins it.
// 2 blocks/CU x 8 waves. 128-byte LDS rows, swz8 slot^=(row&7): zero conflicts.
// BY-FASTEST ordering (r17 showed bx-fastest clusters dead row-blocks and
// starves CUs: occupancy 43->30, -27% time despite lower FETCH). CU feed,
// not HBM traffic, is the binding constraint here.
// ============================================================================
#define STG3(t) do { const int ko=(t)*64;                                      \
    _Pragma("unroll")                                                          \
    for (int p = 0; p < 4; p++)                                                \
      async16(aS[p] + ko, &ldsm[p*4096 + wid*512]);                            \
    _Pragma("unroll")                                                          \
    for (int p = 0; p < 2; p++)                                                \
      async16(bS[p] + ko, &ldsm[16384 + p*4096 + wid*512]);                    \
    } while(0)

#define RD_A(kk, mi) (*(const short8*)&ldsm[(wr*64+(mi)*16+ln15)*64 + ((((kk)*4+g) ^ ((wr*64+(mi)*16+ln15)&7))*8)])
#define RD_B(kk, ni) (*(const short8*)&ldsm[16384 + (wc*64+(ni)*16+ln15)*64 + ((((kk)*4+g) ^ ((wc*64+(ni)*16+ln15)&7))*8)])

__global__ __launch_bounds__(512, 4) void stage_a97(
    const short* __restrict__ xb, const short* __restrict__ wB,
    const float* __restrict__ wgb, const float* __restrict__ w1b,
    const int* __restrict__ counts, const int* __restrict__ lists,
    short* __restrict__ hbuf, int f0chunk, int Fc) {

  // bijective XCD swizzle, BY fastest (steady CU feed; dead bx runs amortized).
  const int NBX = gridDim.x, NBY = gridDim.y;
  const int q = NBX * NBY;
  const int lin = blockIdx.x + NBX * (blockIdx.y + NBY * blockIdx.z);
  const int orig = (lin & 7) * q + (lin >> 3);
  const int e = orig / q;
  const int m = orig - e * q;
  const int by = m % NBY;
  const int bx = m / NBY;

  const int cnt = counts[e];
  const int row0 = bx * 256;
  if (row0 >= cnt) return;
  const int R0 = f0chunk * 2 + by * 128;   // wB row base within expert

  __shared__ short ldsm[24576];   // 48 KB: A 256x64 + B 128x64
  __shared__ int s_pair[256];

  const int tid = threadIdx.x;
  const int wid = tid >> 6;
  const int lane = tid & 63;
  const int ln15 = lane & 15, g = lane >> 4;
  const int wr = wid >> 1, wc = wid & 1;   // 4M x 2N waves, 64x64 each

  if (tid < 256) {
    int r = row0 + tid;
    s_pair[tid] = (r < cnt) ? lists[e*TOK + r] : 0;
  }
  __syncthreads();

  const short* aS[4]; const short* bS[2];
#pragma unroll
  for (int p = 0; p < 4; p++) {
    int j = p * 512 + tid;
    int r = j >> 3;
    int sl = (j & 7) ^ (r & 7);
    aS[p] = xb + (size_t)(s_pair[r] >> 1) * DD + sl * 8;
  }
#pragma unroll
  for (int p = 0; p < 2; p++) {
    int j = p * 512 + tid;
    int r = j >> 3;            // [0,128)
    int sl = (j & 7) ^ (r & 7);
    bS[p] = wB + ((size_t)e * (2*FF) + R0 + r) * DD + sl * 8;
  }

  f32x4 acc[4][4] = {};

  for (int t = 0; t < 16; t++) {
    STG3(t);
    __syncthreads();   // compiler drains vmcnt(0) (m97 semantics)
#pragma unroll
    for (int kk = 0; kk < 2; kk++) {
      short8 a[4], b[4];
#pragma unroll
      for (int mi = 0; mi < 4; mi++) a[mi] = RD_A(kk, mi);
#pragma unroll
      for (int ni = 0; ni < 4; ni++) b[ni] = RD_B(kk, ni);
#pragma unroll
      for (int mi = 0; mi < 4; mi++)
#pragma unroll
        for (int ni = 0; ni < 4; ni++)
          acc[mi][ni] = MFMA_BF16(a[mi], b[ni], acc[mi][ni], 0, 0, 0);
    }
    __syncthreads();
  }

  // epilogue: ni even = hg cols, ni odd = h1 cols, same f.
  const float* wgb_e = wgb + e * FF;
  const float* w1b_e = w1b + e * FF;
  float bgv[2], b1v[2]; int fl[2];
#pragma unroll
  for (int m2 = 0; m2 < 2; m2++) {
    int fg = (R0 + wc*64 + m2*32) / 2 + ln15;
    bgv[m2] = wgb_e[fg];
    b1v[m2] = w1b_e[fg];
    fl[m2] = fg - f0chunk;
  }
#pragma unroll
  for (int mi = 0; mi < 4; mi++) {
    int trb = wr*64 + mi*16 + (g << 2);
#pragma unroll
    for (int m2 = 0; m2 < 2; m2++) {
#pragma unroll
      for (int j = 0; j < 4; j++) {
        int tr = trb + j;
        if (row0 + tr < cnt) {
          int pair = s_pair[tr];
          float hg = acc[mi][2*m2][j] + bgv[m2];
          float h1 = acc[mi][2*m2+1][j] + b1v[m2];
          float gl = 0.5f * hg * (1.f + erff(hg * 0.70710678118f));
          hbuf[(size_t)pair * Fc + fl[m2]] = bfc(gl * h1);
        }
      }
    }
  }
}

// ============================================================================
// stage B: 128x128 tile, BK=64, 33 KB LDS, (256,4) -> 4 blocks/CU x 4 waves.
// BY-FASTEST (see stage A note). ybuf BF16 NT (write-once / read-once).
// ============================================================================
__global__ __launch_bounds__(256, 4) void stage_b97(
    const short* __restrict__ hbuf, const short* __restrict__ w2wb,
    const int* __restrict__ counts, const int* __restrict__ lists,
    short* __restrict__ ybuf, int Fc) {

  const int NBX = gridDim.x, NBY = gridDim.y;
  const int q = NBX * NBY;
  const int lin = blockIdx.x + NBX * (blockIdx.y + NBY * blockIdx.z);
  const int orig = (lin & 7) * q + (lin >> 3);
  const int e = orig / q;
  const int m = orig - e * q;
  const int by = m % NBY;
  const int bx = m / NBY;

  const int cnt = counts[e];
  const int row0 = bx * 128;
  if (row0 >= cnt) return;
  const int d0 = by * 128;

  __shared__ short lA[128 * 64];   // 16 KB
  __shared__ short lB[128 * 64];   // 16 KB
  __shared__ int s_pair[128];

  const int tid = threadIdx.x;
  const int wid = tid >> 6;
  const int lane = tid & 63;
  const int ln15 = lane & 15, g = lane >> 4;
  const int wr = wid >> 1, wc = wid & 1;   // 2M x 2N waves, 64x64 each

  if (tid < 128) {
    int r = row0 + tid;
    s_pair[tid] = (r < cnt) ? lists[e*TOK + r] : 0;
  }
  __syncthreads();

  const short* aS[4]; const short* bS[4];
#pragma unroll
  for (int p = 0; p < 4; p++) {
    int j = p * 256 + tid;
    int r = j >> 3;
    int sl = (j & 7) ^ (r & 7);
    aS[p] = hbuf + (size_t)s_pair[r] * Fc + sl * 8;
    bS[p] = w2wb + ((size_t)e * DD + d0 + r) * FF + sl * 8;
  }

  f32x4 acc[4][4] = {};
  const int NT = Fc >> 6;

  for (int t = 0; t < NT; t++) {
    const int ko = t * 64;
#pragma unroll
    for (int p = 0; p < 4; p++) {
      async16(aS[p] + ko, &lA[p*2048 + wid*512]);
      async16(bS[p] + ko, &lB[p*2048 + wid*512]);
    }
    __syncthreads();
#pragma unroll
    for (int kk = 0; kk < 2; kk++) {
      short8 a[4], b[4];
#pragma unroll
      for (int mi = 0; mi < 4; mi++) {
        int r = wr*64 + mi*16 + ln15;
        a[mi] = *(const short8*)&lA[r*64 + (((kk*4 + g) ^ (r & 7)) * 8)];
      }
#pragma unroll
      for (int ni = 0; ni < 4; ni++) {
        int r = wc*64 + ni*16 + ln15;
        b[ni] = *(const short8*)&lB[r*64 + (((kk*4 + g) ^ (r & 7)) * 8)];
      }
#pragma unroll
      for (int mi = 0; mi < 4; mi++)
#pragma unroll
        for (int ni = 0; ni < 4; ni++)
          acc[mi][ni] = MFMA_BF16(a[mi], b[ni], acc[mi][ni], 0, 0, 0);
    }
    __syncthreads();
  }

  // epilogue: bf16 NT stores (ybuf written-once, streamed once by combine)
#pragma unroll
  for (int mi = 0; mi < 4; mi++) {
    int trb = wr*64 + mi*16 + (g << 2);
#pragma unroll
    for (int j = 0; j < 4; j++) {
      int tr = trb + j;
      if (row0 + tr < cnt) {
        int pair = s_pair[tr];
        short* yrow = ybuf + (size_t)pair * DD;
#pragma unroll
        for (int ni = 0; ni < 4; ni++) {
          int d = d0 + wc*64 + ni*16 + ln15;
          __builtin_nontemporal_store(bfc(acc[mi][ni][j]), &yrow[d]);
        }
      }
    }
  }
}

// ---- combine: out[t] = g0*(y[2t]+b2[e0]) + g1*(y[2t+1]+b2[e1]); y is bf16 ----
__global__ __launch_bounds__(256) void combine_kernel(const short* __restrict__ yb,
    const float* __restrict__ w2b, const float* __restrict__ gates,
    const int* __restrict__ eids, float* __restrict__ out) {
  const int t = blockIdx.x;
  const int tid = threadIdx.x;
  const float g0 = gates[2*t], g1 = gates[2*t+1];
  const int e0 = eids[2*t], e1 = eids[2*t+1];
  short4v y0 = __builtin_nontemporal_load(&((const short4v*)(yb + (size_t)(2*t) * DD))[tid]);
  short4v y1 = __builtin_nontemporal_load(&((const short4v*)(yb + (size_t)(2*t+1) * DD))[tid]);
  f32x4 c0 = ((const f32x4*)(w2b + (size_t)e0 * DD))[tid];
  f32x4 c1 = ((const f32x4*)(w2b + (size_t)e1 * DD))[tid];
  f32x4 o;
#pragma unroll
  for (int i = 0; i < 4; i++) o[i] = g0 * (b2f(y0[i]) + c0[i]) + g1 * (b2f(y1[i]) + c1[i]);
  __builtin_nontemporal_store(o, &((f32x4*)(out + (size_t)t * DD))[tid]);
}

// ================= chunked-Fc fallback: atomic stage B (round-5, proven) =================
#define BB_LDS (128*64)
__global__ __launch_bounds__(256, 2) void stage_b_bf(
    const short* __restrict__ hbuf, const short* __restrict__ w2wb, const float* __restrict__ w2b,
    const int* __restrict__ counts, const int* __restrict__ lists, const float* __restrict__ gates,
    float* __restrict__ out, int f0chunk, int Fc, int addbias) {

  const int lin = blockIdx.x + 64 * (blockIdx.y + 8 * blockIdx.z);
  const int orig = (lin & 7) * 512 + (lin >> 3);
  const int bx = orig & 63;
  const int by = (orig >> 6) & 7;
  const int e  = orig >> 9;

  const int cnt = counts[e];
  const int row0 = bx * 128;
  if (row0 >= cnt) return;
  const int d0 = by * 128;

  __shared__ short lA[2 * BB_LDS];
  __shared__ short lB[2 * BB_LDS];
  __shared__ int s_pair[128];

  const int tid = threadIdx.x;
  const int wid = tid >> 6;
  const int lane = tid & 63;

  if (tid < 128) {
    int r = row0 + tid;
    s_pair[tid] = (r < cnt) ? lists[e*TOK + r] : 0;
  }
  __syncthreads();

  const short* aSrc[4]; const short* bSrc[4];
#pragma unroll
  for (int p = 0; p < 4; p++) {
    int j = p * 256 + tid;
    int r = j >> 3;
    int sl = (j & 7) ^ (r & 7);
    aSrc[p] = hbuf + (size_t)s_pair[r] * Fc + sl * 8;
    bSrc[p] = w2wb + ((size_t)e * DD + d0 + r) * FF + f0chunk + sl * 8;
  }

  f32x4 acc[4][4] = {};
  const int wr = wid >> 1, wc = wid & 1;
  const int NT = Fc >> 6;

#pragma unroll
  for (int p = 0; p < 4; p++) async16(aSrc[p], &lA[p*2048 + wid*512]);
#pragma unroll
  for (int p = 0; p < 4; p++) async16(bSrc[p], &lB[p*2048 + wid*512]);

  for (int t = 0; t < NT; t++) {
    const int cur = t & 1;
    if (t + 1 < NT) {
      const int nb = cur ^ 1;
      const int kf = (t + 1) * 64;
#pragma unroll
      for (int p = 0; p < 4; p++) async16(aSrc[p] + kf, &lA[nb*BB_LDS + p*2048 + wid*512]);
#pragma unroll
      for (int p = 0; p < 4; p++) async16(bSrc[p] + kf, &lB[nb*BB_LDS + p*2048 + wid*512]);
      VMCNT8();
    } else {
      VMCNT0();
    }
    BARRIER();

    const short* LA = lA + cur * BB_LDS;
    const short* LB = lB + cur * BB_LDS;
#pragma unroll
    for (int kk = 0; kk < 2; kk++) {
      short8 a[4], b[4];
#pragma unroll
      for (int mi = 0; mi < 4; mi++) {
        int r = wr*64 + mi*16 + (lane & 15);
        int u = (kk*4 + (lane >> 4)) ^ (r & 7);
        a[mi] = *(const short8*)(LA + r*64 + u*8);
      }
#pragma unroll
      for (int ni = 0; ni < 4; ni++) {
        int r = wc*64 + ni*16 + (lane & 15);
        int u = (kk*4 + (lane >> 4)) ^ (r & 7);
        b[ni] = *(const short8*)(LB + r*64 + u*8);
      }
#pragma unroll
      for (int mi = 0; mi < 4; mi++)
#pragma unroll
        for (int ni = 0; ni < 4; ni++)
          acc[mi][ni] = MFMA_BF16(a[mi], b[ni], acc[mi][ni], 0, 0, 0);
    }
    BARRIER();
  }

  const float* w2b_e = w2b + e * DD;
#pragma unroll
  for (int mi = 0; mi < 4; mi++) {
    int trb = wr*64 + mi*16 + ((lane >> 4) << 2);
#pragma unroll
    for (int j = 0; j < 4; j++) {
      int tr = trb + j;
      if (row0 + tr < cnt) {
        int pair = s_pair[tr];
        int t = pair >> 1;
        float gt = gates[pair];
        float* orow = out + (size_t)t * DD;
#pragma unroll
        for (int ni = 0; ni < 4; ni++) {
          int d = d0 + wc*64 + ni*16 + (lane & 15);
          float v = acc[mi][ni][j] * gt;
          if (addbias) v += w2b_e[d] * gt;
          atomicAdd(orow + d, v);
        }
      }
    }
  }
}

// ================= legacy f32 fallback (tiny ws) =================
__global__ __launch_bounds__(256, 2) void stage_a_f32(
    const float* __restrict__ x, const float* __restrict__ wgw, const float* __restrict__ wgb,
    const float* __restrict__ w1w, const float* __restrict__ w1b,
    const int* __restrict__ counts, const int* __restrict__ lists,
    short* __restrict__ hbuf, int f0chunk, int Fc) {

  const int e = blockIdx.z;
  const int cnt = counts[e];
  const int row0 = blockIdx.x * 128;
  if (row0 >= cnt) return;
  const int fc0 = blockIdx.y * 128;
  const int fg0 = f0chunk + fc0;

  __shared__ float lA[128 * 32];
  __shared__ float lBg[128 * 32];
  __shared__ float lB1[128 * 32];
  __shared__ int s_pair[128];

  const int tid = threadIdx.x;
  const int wid = tid >> 6;
  const int lane = tid & 63;

  if (tid < 128) {
    int r = row0 + tid;
    s_pair[tid] = (r < cnt) ? lists[e*TOK + r] : 0;
  }
  __syncthreads();

  const float* aSrc[4]; const float* gSrc[4]; const float* oSrc[4];
#pragma unroll
  for (int p = 0; p < 4; p++) {
    int j = p * 256 + tid;
    int r = j >> 3;
    int sl = (j & 7) ^ (r & 7);
    aSrc[p] = x + (size_t)(s_pair[r] >> 1) * DD + sl * 4;
    gSrc[p] = wgw + ((size_t)e * FF + fg0 + r) * DD + sl * 4;
    oSrc[p] = w1w + ((size_t)e * FF + fg0 + r) * DD + sl * 4;
  }

  f32x4 accg[4][4] = {}; f32x4 acc1[4][4] = {};
  const int wr = wid >> 1, wc = wid & 1;

  for (int k0 = 0; k0 < DD; k0 += 32) {
#pragma unroll
    for (int p = 0; p < 4; p++) async16(aSrc[p] + k0, &lA[p*1024 + wid*256]);
#pragma unroll
    for (int p = 0; p < 4; p++) async16(gSrc[p] + k0, &lBg[p*1024 + wid*256]);
#pragma unroll
    for (int p = 0; p < 4; p++) async16(oSrc[p] + k0, &lB1[p*1024 + wid*256]);
    __syncthreads();

    short8 a[4], bg[4], b1[4];
#pragma unroll
    for (int mi = 0; mi < 4; mi++) {
      int r = wr*64 + mi*16 + (lane & 15);
      int g2 = (lane >> 4) * 2;
      const f32x4* Ar = (const f32x4*)&lA[r * 32];
      a[mi] = cvt8(Ar[g2 ^ (r & 7)], Ar[(g2 + 1) ^ (r & 7)]);
    }
#pragma unroll
    for (int ni = 0; ni < 4; ni++) {
      int r = wc*64 + ni*16 + (lane & 15);
      int g2 = (lane >> 4) * 2;
      const f32x4* Bg = (const f32x4*)&lBg[r * 32];
      const f32x4* B1 = (const f32x4*)&lB1[r * 32];
      bg[ni] = cvt8(Bg[g2 ^ (r & 7)], Bg[(g2 + 1) ^ (r & 7)]);
      b1[ni] = cvt8(B1[g2 ^ (r & 7)], B1[(g2 + 1) ^ (r & 7)]);
    }
#pragma unroll
    for (int mi = 0; mi < 4; mi++)
#pragma unroll
      for (int ni = 0; ni < 4; ni++) {
        accg[mi][ni] = MFMA_BF16(a[mi], bg[ni], accg[mi][ni], 0, 0, 0);
        acc1[mi][ni] = MFMA_BF16(a[mi], b1[ni], acc1[mi][ni], 0, 0, 0);
      }
    __syncthreads();
  }

  const float* wgb_e = wgb + e * FF;
  const float* w1b_e = w1b + e * FF;
#pragma unroll
  for (int mi = 0; mi < 4; mi++) {
    int trb = wr*64 + mi*16 + ((lane >> 4) << 2);
#pragma unroll
    for (int ni = 0; ni < 4; ni++) {
      int c = wc*64 + ni*16 + (lane & 15);
      float bgv = wgb_e[fg0 + c];
      float b1v = w1b_e[fg0 + c];
#pragma unroll
      for (int j = 0; j < 4; j++) {
        int tr = trb + j;
        if (row0 + tr < cnt) {
          int pair = s_pair[tr];
          float hg = accg[mi][ni][j] + bgv;
          float h1 = acc1[mi][ni][j] + b1v;
          float gl = 0.5f * hg * (1.f + erff(hg * 0.70710678118f));
          hbuf[(size_t)pair * Fc + fc0 + c] = bfc(gl * h1);
        }
      }
    }
  }
}

__global__ __launch_bounds__(256, 2) void stage_b_f32(
    const short* __restrict__ hbuf, const float* __restrict__ w2w, const float* __restrict__ w2b,
    const int* __restrict__ counts, const int* __restrict__ lists, const float* __restrict__ gates,
    float* __restrict__ out, int f0chunk, int Fc, int addbias) {

  const int e = blockIdx.z;
  const int cnt = counts[e];
  const int row0 = blockIdx.x * 128;
  if (row0 >= cnt) return;
  const int d0 = blockIdx.y * 128;

  __shared__ short lA[128 * 64];
  __shared__ float lB[128 * 64];
  __shared__ int s_pair[128];

  const int tid = threadIdx.x;
  const int wid = tid >> 6;
  const int lane = tid & 63;

  if (tid < 128) {
    int r = row0 + tid;
    s_pair[tid] = (r < cnt) ? lists[e*TOK + r] : 0;
  }
  __syncthreads();

  const short* aSrc[4];
#pragma unroll
  for (int p = 0; p < 4; p++) {
    int j = p * 256 + tid;
    int r = j >> 3;
    int sl = (j & 7) ^ (r & 7);
    aSrc[p] = hbuf + (size_t)s_pair[r] * Fc + sl * 8;
  }
  const float* bSrc[8];
#pragma unroll
  for (int p = 0; p < 8; p++) {
    int j = p * 256 + tid;
    int r = j >> 4;
    int sl = (j & 15) ^ (r & 7);
    bSrc[p] = w2w + ((size_t)e * DD + d0 + r) * FF + f0chunk + sl * 4;
  }

  f32x4 acc[4][4] = {};
  const int wr = wid >> 1, wc = wid & 1;

  for (int kf = 0; kf < Fc; kf += 64) {
#pragma unroll
    for (int p = 0; p < 4; p++) async16(aSrc[p] + kf, &lA[p*2048 + wid*512]);
#pragma unroll
    for (int p = 0; p < 8; p++) async16(bSrc[p] + kf, &lB[p*1024 + wid*256]);
    __syncthreads();

#pragma unroll
    for (int kk = 0; kk < 2; kk++) {
      short8 a[4]; short8 b[4];
#pragma unroll
      for (int mi = 0; mi < 4; mi++) {
        int r = wr*64 + mi*16 + (lane & 15);
        int u = (kk*4 + (lane >> 4)) ^ (r & 7);
        a[mi] = ((const short8*)(lA + r * 64))[u];
      }
#pragma unroll
      for (int ni = 0; ni < 4; ni++) {
        int r = wc*64 + ni*16 + (lane & 15);
        int g2 = (kk*4 + (lane >> 4)) * 2;
        const f32x4* Br = (const f32x4*)(lB + r * 64);
        b[ni] = cvt8(Br[g2 ^ (r & 7)], Br[(g2 + 1) ^ (r & 7)]);
      }
#pragma unroll
      for (int mi = 0; mi < 4; mi++)
#pragma unroll
        for (int ni = 0; ni < 4; ni++)
          acc[mi][ni] = MFMA_BF16(a[mi], b[ni], acc[mi][ni], 0, 0, 0);
    }
    __syncthreads();
  }

  const float* w2b_e = w2b + e * DD;
#pragma unroll
  for (int mi = 0; mi < 4; mi++) {
    int trb = wr*64 + mi*16 + ((lane >> 4) << 2);
#pragma unroll
    for (int j = 0; j < 4; j++) {
      int tr = trb + j;
      if (row0 + tr < cnt) {
        int pair = s_pair[tr];
        int t = pair >> 1;
        float gt = gates[pair];
        float* orow = out + (size_t)t * DD;
#pragma unroll
        for (int ni = 0; ni < 4; ni++) {
          int d = d0 + wc*64 + ni*16 + (lane & 15);
          float v = acc[mi][ni][j] * gt;
          if (addbias) v += w2b_e[d] * gt;
          atomicAdd(orow + d, v);
        }
      }
    }
  }
}

extern "C" void kernel_launch(void* const* d_in, const int* in_sizes, int n_in,
                              void* d_out, int out_size, void* d_ws, size_t ws_size,
                              hipStream_t stream) {
  const float* x   = (const float*)d_in[0];
  const float* rw  = (const float*)d_in[1];
  const float* w1w = (const float*)d_in[2];
  const float* w1b = (const float*)d_in[3];
  const float* w2w = (const float*)d_in[4];
  const float* w2b = (const float*)d_in[5];
  const float* wgw = (const float*)d_in[6];
  const float* wgb = (const float*)d_in[7];
  float* out = (float*)d_out;

  char* ws = (char*)d_ws;
  size_t off = 0;
  int* counts = (int*)(ws + off); off += 128;
  int* lists  = (int*)(ws + off); off += (size_t)EE * TOK * 4;
  float* gates = (float*)(ws + off); off += (size_t)NPAIR * 4;
  int* eids = (int*)(ws + off); off += (size_t)NPAIR * 4;
  const size_t base0 = off;

  const size_t WELEM = (size_t)EE * FF * DD;
  const size_t bf_need = base0 + (size_t)TOK*DD*2 + 2*WELEM*2 + WELEM*2;

  hipMemsetAsync(counts, 0, 128, stream);

  const int cands[6] = {4096, 2048, 1024, 512, 256, 128};

  if (bf_need + (size_t)NPAIR * 128 * 2 <= ws_size) {
    // ---- bf16 path ----
    off = base0;
    short* xb   = (short*)(ws + off); off += (size_t)TOK * DD * 2;
    short* wB   = (short*)(ws + off); off += 2 * WELEM * 2;   // interleaved wg/w1
    short* w2wb = (short*)(ws + off); off += WELEM * 2;
    short* hbuf = (short*)(ws + off);
    short* ybuf = (short*)wB;   // alias: wB dead after last stage_a (Fc==4096 only);
                                // cvt_interleave fully rewrites wB every call.

    int Fc = 128;
    for (int i = 0; i < 6; i++)
      if (off + (size_t)NPAIR * cands[i] * 2 <= ws_size) { Fc = cands[i]; break; }

    router_kernel<<<dim3(TOK), dim3(64), 0, stream>>>(x, rw, counts, lists, gates, eids, xb, 1);
    cvt_interleave<<<dim3(EE*FF), dim3(256), 0, stream>>>(wgw, w1w, wB);
    cvt_bf16_kernel<<<dim3(2048), dim3(256), 0, stream>>>(w2w, w2wb, (int)(WELEM/8));

    if (Fc == 4096) {
      // single chunk: stage_a 256x128 + stage_b 128x128 (4 blocks/CU), combine
      stage_a97<<<dim3(32, (2*Fc)/128, EE), dim3(512), 0, stream>>>(
          xb, wB, wgb, w1b, counts, lists, hbuf, 0, Fc);
      stage_b97<<<dim3(64, DD/128, EE), dim3(256), 0, stream>>>(
          hbuf, w2wb, counts, lists, ybuf, Fc);
      combine_kernel<<<dim3(TOK), dim3(256), 0, stream>>>(ybuf, w2b, gates, eids, out);
    } else {
      // chunked: stage_a + atomic stage_b
      hipMemsetAsync(out, 0, (size_t)TOK * DD * 4, stream);
      for (int f0 = 0; f0 < FF; f0 += Fc) {
        stage_a97<<<dim3(32, (2*Fc)/128, EE), dim3(512), 0, stream>>>(
            xb, wB, wgb, w1b, counts, lists, hbuf, f0, Fc);
        stage_b_bf<<<dim3(64, DD/128, EE), dim3(256), 0, stream>>>(
            hbuf, w2wb, w2b, counts, lists, gates, out, f0, Fc, f0 == 0);
      }
    }
  } else {
    // ---- legacy f32 path ----
    short* hbuf = (short*)(ws + base0);
    int Fc = 128;
    for (int i = 0; i < 6; i++)
      if (base0 + (size_t)NPAIR * cands[i] * 2 <= ws_size) { Fc = cands[i]; break; }

    hipMemsetAsync(out, 0, (size_t)TOK * DD * 4, stream);
    router_kernel<<<dim3(TOK), dim3(64), 0, stream>>>(x, rw, counts, lists, gates, eids, nullptr, 0);

    for (int f0 = 0; f0 < FF; f0 += Fc) {
      dim3 ga(64, Fc / 128, EE);
      stage_a_f32<<<ga, dim3(256), 0, stream>>>(x, wgw, wgb, w1w, w1b, counts, lists, hbuf, f0, Fc);
      dim3 gb(64, DD / 128, EE);
      stage_b_f32<<<gb, dim3(256), 0, stream>>>(hbuf, w2w, w2b, counts, lists, gates, out, f0, Fc, f0 == 0);
    }
  }
}